// Round 4
// baseline (520.492 us; speedup 1.0000x reference)
//
#include <hip/hip_runtime.h>
#include <hip/hip_bf16.h>

typedef __bf16 bf16_t;
typedef __bf16 bf16x8 __attribute__((ext_vector_type(8)));
typedef float  f32x4  __attribute__((ext_vector_type(4)));
typedef int    i32x4  __attribute__((ext_vector_type(4)));

#define M_DIM 4096
#define N_DIM 12288
#define K_DIM 3072
#define NBLK  96      // K_DIM / 32 quant blocks per output row

// depth-2 pipelined GEMM geometry
#define BM 256
#define BN 128
#define BK 64
#define THREADS 512
#define NT (K_DIM / BK)   // 48 K-tiles
#define NBUF 3
#define ASZ (BM * BK)     // 16384 elems = 32 KB
#define BSZ (BN * BK)     //  8192 elems = 16 KB

// ws layout: W_bf16 [N][K] at 0 (75.5 MB), X_bf16 [M][K] after (25.2 MB)
#define W_BYTES ((size_t)N_DIM * K_DIM * 2)
#define X_BYTES ((size_t)M_DIM * K_DIM * 2)

__device__ __forceinline__ void gload_lds16(const void* g, void* l) {
    // async global->LDS, 16B/lane; LDS dest = wave-uniform base + lane*16
    __builtin_amdgcn_global_load_lds(
        (const __attribute__((address_space(1))) unsigned int*)g,
        (__attribute__((address_space(3))) unsigned int*)l, 16, 0, 0);
}

// ---------------- Pass 1a: dequant Q8_0 weights -> bf16 ----------------
__global__ __launch_bounds__(256) void dequant_w_kernel(
    const int* __restrict__ wq, const float* __restrict__ scales,
    bf16_t* __restrict__ W)
{
    unsigned c = blockIdx.x * 256u + threadIdx.x;   // 8-elem chunk id
    unsigned o  = c / 384u;                         // 384 chunks per row
    unsigned kc = c - o * 384u;
    float s = scales[o * NBLK + (kc >> 2)];
    const int* gq = wq + (size_t)c * 8;
    i32x4 q0 = *(const i32x4*)gq;
    i32x4 q1 = *(const i32x4*)(gq + 4);
    bf16x8 v;
    v[0] = (bf16_t)((float)q0[0] * s); v[1] = (bf16_t)((float)q0[1] * s);
    v[2] = (bf16_t)((float)q0[2] * s); v[3] = (bf16_t)((float)q0[3] * s);
    v[4] = (bf16_t)((float)q1[0] * s); v[5] = (bf16_t)((float)q1[1] * s);
    v[6] = (bf16_t)((float)q1[2] * s); v[7] = (bf16_t)((float)q1[3] * s);
    *(bf16x8*)&W[(size_t)c * 8] = v;
}

// ---------------- Pass 1b: x fp32 -> bf16 ----------------
__global__ __launch_bounds__(256) void cvt_x_kernel(
    const float* __restrict__ x, bf16_t* __restrict__ X)
{
    unsigned c = blockIdx.x * 256u + threadIdx.x;
    const float* gp = x + (size_t)c * 8;
    f32x4 f0 = *(const f32x4*)gp;
    f32x4 f1 = *(const f32x4*)(gp + 4);
    bf16x8 v;
    v[0] = (bf16_t)f0[0]; v[1] = (bf16_t)f0[1];
    v[2] = (bf16_t)f0[2]; v[3] = (bf16_t)f0[3];
    v[4] = (bf16_t)f1[0]; v[5] = (bf16_t)f1[1];
    v[6] = (bf16_t)f1[2]; v[7] = (bf16_t)f1[3];
    *(bf16x8*)&X[(size_t)c * 8] = v;
}

// ---------------- Pass 2: depth-2 counted-vmcnt pipelined bf16 GEMM ----------
// C[t][o] = sum_k X[t][k] * W[o][k] + bias[o]
// 3 LDS buffers; tile t in slot t%3. Iteration t: wait vmcnt(6) (tile t landed,
// t+1's 6 loads stay in flight), barrier (also proves slot (t+2)%3 consumed),
// issue tile t+2, compute tile t in 2 barrier-split 16-MFMA phases (T3/T5).
// Swizzle both-sides (rule #21): linear LDS chunk (row,c8) holds global chunk
// (row, c8^(row&7)) via pre-swizzled global source; reads XOR the same.
__global__ __launch_bounds__(THREADS, 2) void gemm_pipe_kernel(
    const bf16_t* __restrict__ A, const bf16_t* __restrict__ B,
    const float* __restrict__ bias, float* __restrict__ out)
{
    __shared__ __align__(16) bf16_t sA[NBUF][ASZ];   // 3 x 32 KB
    __shared__ __align__(16) bf16_t sB[NBUF][BSZ];   // 3 x 16 KB -> 144 KB

    const int tid  = threadIdx.x;
    const int bm   = blockIdx.x / (N_DIM / BN);
    const int bn   = blockIdx.x % (N_DIM / BN);
    const int row0 = bm * BM;
    const int col0 = bn * BN;

    const int lane = tid & 63;
    const int wid  = tid >> 6;          // 8 waves: 4 (M) x 2 (N)
    const int wr   = (wid >> 1) * 64;   // wave row offset in tile
    const int wc   = (wid & 1) * 64;    // wave col offset in tile
    const int fr   = lane & 15;         // fragment row within 16
    const int kq   = lane >> 4;         // k-chunk quarter 0..3

    // staging: thread owns A chunks (row=j*64+rws, c8=tid&7) j=0..3, B j=0..1
    const int rws = tid >> 3;                         // 0..63
    const int c8g = (tid & 7) ^ (rws & 7);            // pre-swizzled src chunk
    const bf16_t* srcA = A + (size_t)(row0 + rws) * K_DIM + c8g * 8;
    const bf16_t* srcB = B + (size_t)(col0 + rws) * K_DIM + c8g * 8;

    auto issueA = [&](int slot, int tt, int j) {
        gload_lds16(srcA + (size_t)tt * BK + (size_t)j * 64 * K_DIM,
                    &sA[slot][wid * 512 + j * 4096]);
    };
    auto issueB = [&](int slot, int tt, int j) {
        gload_lds16(srcB + (size_t)tt * BK + (size_t)j * 64 * K_DIM,
                    &sB[slot][wid * 512 + j * 4096]);
    };

    f32x4 acc[4][4];
#pragma unroll
    for (int m = 0; m < 4; ++m)
#pragma unroll
        for (int n = 0; n < 4; ++n) acc[m][n] = (f32x4)0.f;

    // ---- prologue: stage tiles 0 and 1 (12 loads in flight) ----
#pragma unroll
    for (int j = 0; j < 4; ++j) issueA(0, 0, j);
#pragma unroll
    for (int j = 0; j < 2; ++j) issueB(0, 0, j);
#pragma unroll
    for (int j = 0; j < 4; ++j) issueA(1, 1, j);
#pragma unroll
    for (int j = 0; j < 2; ++j) issueB(1, 1, j);

    int cur = 0;
    for (int t = 0; t < NT; ++t) {
        // tile t landed; tile t+1's 6 loads remain in flight (T4: never 0)
        asm volatile("s_waitcnt vmcnt(6)\n\ts_barrier" ::: "memory");

        int slot2 = cur + 2; if (slot2 >= NBUF) slot2 -= NBUF;
        int tn = t + 2; if (tn >= NT) tn -= NT;   // tail: benign dummy refetch

        const bf16_t* pA = &sA[cur][0];
        const bf16_t* pB = &sB[cur][0];

        // ---- phase 0: issue 3 stage loads, read af + bg(n=0,1), 16 MFMA ----
        issueA(slot2, tn, 0); issueA(slot2, tn, 1); issueB(slot2, tn, 0);

        bf16x8 af[4][2], bg[2][2];
#pragma unroll
        for (int m = 0; m < 4; ++m) {
            int row = wr + m * 16 + fr;
#pragma unroll
            for (int ks = 0; ks < 2; ++ks) {
                int kc = ks * 4 + kq;
                af[m][ks] = *(const bf16x8*)(pA + row * BK + ((kc ^ (row & 7)) << 3));
            }
        }
#pragma unroll
        for (int n = 0; n < 2; ++n) {
            int row = wc + n * 16 + fr;
#pragma unroll
            for (int ks = 0; ks < 2; ++ks) {
                int kc = ks * 4 + kq;
                bg[n][ks] = *(const bf16x8*)(pB + row * BK + ((kc ^ (row & 7)) << 3));
            }
        }
        __builtin_amdgcn_s_setprio(1);
#pragma unroll
        for (int m = 0; m < 4; ++m)
#pragma unroll
            for (int n = 0; n < 2; ++n)
#pragma unroll
                for (int ks = 0; ks < 2; ++ks)
                    acc[m][n] = __builtin_amdgcn_mfma_f32_16x16x32_bf16(
                        af[m][ks], bg[n][ks], acc[m][n], 0, 0, 0);
        __builtin_amdgcn_s_setprio(0);

        asm volatile("s_barrier" ::: "memory");   // phase split (role diversity)

        // ---- phase 1: issue 3 stage loads, read bg(n=2,3), 16 MFMA ----
        issueA(slot2, tn, 2); issueA(slot2, tn, 3); issueB(slot2, tn, 1);

        bf16x8 bh[2][2];
#pragma unroll
        for (int n = 0; n < 2; ++n) {
            int row = wc + 32 + n * 16 + fr;
#pragma unroll
            for (int ks = 0; ks < 2; ++ks) {
                int kc = ks * 4 + kq;
                bh[n][ks] = *(const bf16x8*)(pB + row * BK + ((kc ^ (row & 7)) << 3));
            }
        }
        __builtin_amdgcn_s_setprio(1);
#pragma unroll
        for (int m = 0; m < 4; ++m)
#pragma unroll
            for (int n = 0; n < 2; ++n)
#pragma unroll
                for (int ks = 0; ks < 2; ++ks)
                    acc[m][n + 2] = __builtin_amdgcn_mfma_f32_16x16x32_bf16(
                        af[m][ks], bh[n][ks], acc[m][n + 2], 0, 0, 0);
        __builtin_amdgcn_s_setprio(0);

        cur = cur + 1; if (cur >= NBUF) cur -= NBUF;
    }

    // ---- epilogue: C/D layout col=lane&15, row=(lane>>4)*4+j ----
    const int crow = (lane >> 4) << 2;
    const int ccol = lane & 15;
#pragma unroll
    for (int m = 0; m < 4; ++m) {
#pragma unroll
        for (int n = 0; n < 4; ++n) {
            int col = col0 + wc + n * 16 + ccol;
            float b = bias[col];
#pragma unroll
            for (int j = 0; j < 4; ++j) {
                int row = row0 + wr + m * 16 + crow + j;
                out[(size_t)row * N_DIM + col] = acc[m][n][j] + b;
            }
        }
    }
}

// ---------------- Fallback: fused kernel (if ws too small) ----------------
#define FBM 128
#define FBN 128
#define FTHREADS 256
__global__ __launch_bounds__(FTHREADS) void dq_gemm_fused_kernel(
    const float* __restrict__ x, const int* __restrict__ wq,
    const float* __restrict__ scales, const float* __restrict__ bias,
    float* __restrict__ out)
{
    __shared__ bf16_t fA[FBM * BK];
    __shared__ bf16_t fB[FBN * BK];

    const int tid  = threadIdx.x;
    const int bm   = blockIdx.x / (N_DIM / FBN);
    const int bn   = blockIdx.x % (N_DIM / FBN);
    const int row0 = bm * FBM;
    const int col0 = bn * FBN;
    const int lane = tid & 63;
    const int wid  = tid >> 6;
    const int wr   = (wid >> 1) * 64;
    const int wc   = (wid & 1) * 64;
    const int fr   = lane & 15;
    const int fk   = (lane >> 4) << 3;

    f32x4 acc[4][4];
#pragma unroll
    for (int m = 0; m < 4; ++m)
#pragma unroll
        for (int n = 0; n < 4; ++n) acc[m][n] = (f32x4)0.f;

    for (int kt = 0; kt < K_DIM / BK; ++kt) {
        const int kb = kt * BK;
#pragma unroll
        for (int c = 0; c < 4; ++c) {
            int i  = c * FTHREADS + tid;
            int r  = i >> 3;
            int k0 = (i & 7) << 3;
            const float* gp = x + (size_t)(row0 + r) * K_DIM + kb + k0;
            f32x4 f0 = *(const f32x4*)gp;
            f32x4 f1 = *(const f32x4*)(gp + 4);
            bf16x8 v;
            v[0] = (bf16_t)f0[0]; v[1] = (bf16_t)f0[1];
            v[2] = (bf16_t)f0[2]; v[3] = (bf16_t)f0[3];
            v[4] = (bf16_t)f1[0]; v[5] = (bf16_t)f1[1];
            v[6] = (bf16_t)f1[2]; v[7] = (bf16_t)f1[3];
            *(bf16x8*)&fA[r * BK + (k0 ^ ((r & 7) << 3))] = v;
        }
#pragma unroll
        for (int c = 0; c < 4; ++c) {
            int i  = c * FTHREADS + tid;
            int r  = i >> 3;
            int k0 = (i & 7) << 3;
            int o  = col0 + r;
            const int* gq = wq + (size_t)o * K_DIM + kb + k0;
            i32x4 q0 = *(const i32x4*)gq;
            i32x4 q1 = *(const i32x4*)(gq + 4);
            float s = scales[o * NBLK + ((kb + k0) >> 5)];
            bf16x8 v;
            v[0] = (bf16_t)((float)q0[0] * s); v[1] = (bf16_t)((float)q0[1] * s);
            v[2] = (bf16_t)((float)q0[2] * s); v[3] = (bf16_t)((float)q0[3] * s);
            v[4] = (bf16_t)((float)q1[0] * s); v[5] = (bf16_t)((float)q1[1] * s);
            v[6] = (bf16_t)((float)q1[2] * s); v[7] = (bf16_t)((float)q1[3] * s);
            *(bf16x8*)&fB[r * BK + (k0 ^ ((r & 7) << 3))] = v;
        }
        __syncthreads();
#pragma unroll
        for (int ks = 0; ks < 2; ++ks) {
            bf16x8 af[4], bg[4];
#pragma unroll
            for (int m = 0; m < 4; ++m) {
                int r = wr + m * 16 + fr;
                af[m] = *(const bf16x8*)&fA[r * BK + ((ks * 32 + fk) ^ ((r & 7) << 3))];
            }
#pragma unroll
            for (int n = 0; n < 4; ++n) {
                int r = wc + n * 16 + fr;
                bg[n] = *(const bf16x8*)&fB[r * BK + ((ks * 32 + fk) ^ ((r & 7) << 3))];
            }
#pragma unroll
            for (int m = 0; m < 4; ++m)
#pragma unroll
                for (int n = 0; n < 4; ++n)
                    acc[m][n] = __builtin_amdgcn_mfma_f32_16x16x32_bf16(
                        af[m], bg[n], acc[m][n], 0, 0, 0);
        }
        __syncthreads();
    }

    const int crow = (lane >> 4) << 2;
    const int ccol = lane & 15;
#pragma unroll
    for (int m = 0; m < 4; ++m) {
#pragma unroll
        for (int n = 0; n < 4; ++n) {
            int col = col0 + wc + n * 16 + ccol;
            float b = bias[col];
#pragma unroll
            for (int j = 0; j < 4; ++j) {
                int row = row0 + wr + m * 16 + crow + j;
                out[(size_t)row * N_DIM + col] = acc[m][n][j] + b;
            }
        }
    }
}

extern "C" void kernel_launch(void* const* d_in, const int* in_sizes, int n_in,
                              void* d_out, int out_size, void* d_ws, size_t ws_size,
                              hipStream_t stream) {
    const float* x      = (const float*)d_in[0];
    const int*   wq     = (const int*)d_in[1];
    const float* scales = (const float*)d_in[2];
    const float* bias   = (const float*)d_in[3];
    float*       out    = (float*)d_out;

    if (ws_size >= W_BYTES + X_BYTES) {
        bf16_t* W = (bf16_t*)d_ws;
        bf16_t* X = (bf16_t*)((char*)d_ws + W_BYTES);
        dequant_w_kernel<<<dim3(N_DIM * K_DIM / 8 / 256), dim3(256), 0, stream>>>(wq, scales, W);
        cvt_x_kernel<<<dim3(M_DIM * K_DIM / 8 / 256), dim3(256), 0, stream>>>(x, X);
        gemm_pipe_kernel<<<dim3((M_DIM / BM) * (N_DIM / BN)), dim3(THREADS), 0, stream>>>(X, W, bias, out);
    } else {
        dq_gemm_fused_kernel<<<dim3((M_DIM / FBM) * (N_DIM / FBN)), dim3(FTHREADS), 0, stream>>>(
            x, wq, scales, bias, out);
    }
}

// Round 5
// 368.430 us; speedup vs baseline: 1.4127x; 1.4127x over previous
//
#include <hip/hip_runtime.h>
#include <hip/hip_bf16.h>

typedef __bf16 bf16_t;
typedef __bf16 bf16x8 __attribute__((ext_vector_type(8)));
typedef float  f32x4  __attribute__((ext_vector_type(4)));
typedef int    i32x4  __attribute__((ext_vector_type(4)));

#define M_DIM 4096
#define N_DIM 12288
#define K_DIM 3072
#define NBLK  96      // K_DIM / 32 quant blocks per output row

// 256x256 phased GEMM geometry (round-3 geometry: per-wave 128x64 = 42.7 FLOP/LDS-byte)
#define BM 256
#define BN 256
#define BK 64
#define THREADS 512
#define NT (K_DIM / BK)   // 48 K-tiles

// ws layout: W_bf16 [N][K] at 0 (75.5 MB), X_bf16 [M][K] after (25.2 MB)
#define W_BYTES ((size_t)N_DIM * K_DIM * 2)
#define X_BYTES ((size_t)M_DIM * K_DIM * 2)

__device__ __forceinline__ void gload_lds16(const void* g, void* l) {
    // async global->LDS, 16B/lane; LDS dest = wave-uniform base + lane*16
    __builtin_amdgcn_global_load_lds(
        (const __attribute__((address_space(1))) unsigned int*)g,
        (__attribute__((address_space(3))) unsigned int*)l, 16, 0, 0);
}

// ---------------- Pass 1a: dequant Q8_0 weights -> bf16 ----------------
__global__ __launch_bounds__(256) void dequant_w_kernel(
    const int* __restrict__ wq, const float* __restrict__ scales,
    bf16_t* __restrict__ W)
{
    unsigned c = blockIdx.x * 256u + threadIdx.x;   // 8-elem chunk id
    unsigned o  = c / 384u;                         // 384 chunks per row
    unsigned kc = c - o * 384u;
    float s = scales[o * NBLK + (kc >> 2)];
    const int* gq = wq + (size_t)c * 8;
    i32x4 q0 = *(const i32x4*)gq;
    i32x4 q1 = *(const i32x4*)(gq + 4);
    bf16x8 v;
    v[0] = (bf16_t)((float)q0[0] * s); v[1] = (bf16_t)((float)q0[1] * s);
    v[2] = (bf16_t)((float)q0[2] * s); v[3] = (bf16_t)((float)q0[3] * s);
    v[4] = (bf16_t)((float)q1[0] * s); v[5] = (bf16_t)((float)q1[1] * s);
    v[6] = (bf16_t)((float)q1[2] * s); v[7] = (bf16_t)((float)q1[3] * s);
    *(bf16x8*)&W[(size_t)c * 8] = v;
}

// ---------------- Pass 1b: x fp32 -> bf16 ----------------
__global__ __launch_bounds__(256) void cvt_x_kernel(
    const float* __restrict__ x, bf16_t* __restrict__ X)
{
    unsigned c = blockIdx.x * 256u + threadIdx.x;
    const float* gp = x + (size_t)c * 8;
    f32x4 f0 = *(const f32x4*)gp;
    f32x4 f1 = *(const f32x4*)(gp + 4);
    bf16x8 v;
    v[0] = (bf16_t)f0[0]; v[1] = (bf16_t)f0[1];
    v[2] = (bf16_t)f0[2]; v[3] = (bf16_t)f0[3];
    v[4] = (bf16_t)f1[0]; v[5] = (bf16_t)f1[1];
    v[6] = (bf16_t)f1[2]; v[7] = (bf16_t)f1[3];
    *(bf16x8*)&X[(size_t)c * 8] = v;
}

// ---------------- Pass 2: 256^2 4-phase pipelined bf16 GEMM ----------------
// C[t][o] = sum_k X[t][k] * W[o][k] + bias[o]
// Round-3 base (issue 8 -> vmcnt(8) -> barrier, depth-8 in flight) + T3
// phase-split: 4 phases x 16 MFMA (quadrants of per-wave 128x64), ds_reads
// per phase, s_barrier per phase -> wave role diversity (T5 setprio active).
// Swizzle both-sides (rule #21): linear LDS chunk (row,c8) holds global chunk
// (row, c8^(row&7)) via pre-swizzled global source; reads XOR the same.
__global__ __launch_bounds__(THREADS, 2) void gemm256_kernel(
    const bf16_t* __restrict__ A, const bf16_t* __restrict__ B,
    const float* __restrict__ bias, float* __restrict__ out)
{
    __shared__ __align__(16) bf16_t sA[2][BM * BK];   // 2 x 32 KB
    __shared__ __align__(16) bf16_t sB[2][BN * BK];   // 2 x 32 KB -> 128 KB

    const int tid = threadIdx.x;
    // T1: XCD-aware swizzle (nwg = 768, 768 % 8 == 0 -> simple form bijective)
    const int nwg  = (M_DIM / BM) * (N_DIM / BN);
    const int bid  = blockIdx.x;
    const int wg   = (bid & 7) * (nwg >> 3) + (bid >> 3);
    const int bm   = wg / (N_DIM / BN);
    const int bn   = wg % (N_DIM / BN);
    const int row0 = bm * BM;
    const int col0 = bn * BN;

    const int lane = tid & 63;
    const int wid  = tid >> 6;          // 8 waves: 2 (M) x 4 (N)
    const int wr   = (wid >> 2) * 128;  // wave row offset in tile
    const int wc   = (wid & 3) * 64;    // wave col offset in tile
    const int fr   = lane & 15;         // fragment row within 16
    const int kq   = lane >> 4;         // k-chunk quarter 0..3

    // staging: thread owns chunk (row = j*64 + (tid>>3), c8 = tid&7), j=0..3
    const int rws = tid >> 3;                         // 0..63
    const int c8g = (tid & 7) ^ (rws & 7);            // pre-swizzled src chunk
    const bf16_t* srcA = A + (size_t)(row0 + rws) * K_DIM + c8g * 8;
    const bf16_t* srcB = B + (size_t)(col0 + rws) * K_DIM + c8g * 8;
    const int ldsBase = wid * 512;                    // elems; +j*4096 per issue

    f32x4 acc[8][4];
#pragma unroll
    for (int m = 0; m < 8; ++m)
#pragma unroll
        for (int n = 0; n < 4; ++n) acc[m][n] = (f32x4)0.f;

    // ---- prologue: stage tile 0 into buf 0 ----
#pragma unroll
    for (int j = 0; j < 4; ++j) {
        gload_lds16(srcA + (size_t)j * 64 * K_DIM, &sA[0][ldsBase + j * 4096]);
        gload_lds16(srcB + (size_t)j * 64 * K_DIM, &sB[0][ldsBase + j * 4096]);
    }

    for (int t = 0; t < NT; ++t) {
        const int cur = t & 1;
        const int nxt = cur ^ 1;
        const int tn  = (t + 1 < NT) ? (t + 1) : 0;   // tail dummy refetch: benign

        // ---- issue all 8 stage loads for tile t+1 (depth-8 in flight) ----
        const bf16_t* Asrc = srcA + (size_t)tn * BK;
        const bf16_t* Bsrc = srcB + (size_t)tn * BK;
#pragma unroll
        for (int j = 0; j < 4; ++j) {
            gload_lds16(Asrc + (size_t)j * 64 * K_DIM, &sA[nxt][ldsBase + j * 4096]);
            gload_lds16(Bsrc + (size_t)j * 64 * K_DIM, &sB[nxt][ldsBase + j * 4096]);
        }

        // tile t landed; tile t+1's 8 stay in flight (T4: never 0)
        asm volatile("s_waitcnt vmcnt(8)\n\ts_barrier" ::: "memory");

        const bf16_t* pA = &sA[cur][0];
        const bf16_t* pB = &sB[cur][0];

        // ---- ph0: read af0 (8) + bg0 (4); MFMA q(0,0); BAR ----
        bf16x8 af0[4][2], af1[4][2], bg0[2][2], bg1[2][2];
#pragma unroll
        for (int m = 0; m < 4; ++m) {
            int row = wr + m * 16 + fr;
#pragma unroll
            for (int ks = 0; ks < 2; ++ks) {
                int kc = ks * 4 + kq;
                af0[m][ks] = *(const bf16x8*)(pA + row * BK + ((kc ^ (row & 7)) << 3));
            }
        }
#pragma unroll
        for (int n = 0; n < 2; ++n) {
            int row = wc + n * 16 + fr;
#pragma unroll
            for (int ks = 0; ks < 2; ++ks) {
                int kc = ks * 4 + kq;
                bg0[n][ks] = *(const bf16x8*)(pB + row * BK + ((kc ^ (row & 7)) << 3));
            }
        }
        __builtin_amdgcn_s_setprio(1);
#pragma unroll
        for (int m = 0; m < 4; ++m)
#pragma unroll
            for (int n = 0; n < 2; ++n)
#pragma unroll
                for (int ks = 0; ks < 2; ++ks)
                    acc[m][n] = __builtin_amdgcn_mfma_f32_16x16x32_bf16(
                        af0[m][ks], bg0[n][ks], acc[m][n], 0, 0, 0);
        __builtin_amdgcn_s_setprio(0);
        asm volatile("s_barrier" ::: "memory");

        // ---- ph1: read bg1 (4); MFMA q(0,1) = af0 x bg1; BAR ----
#pragma unroll
        for (int n = 0; n < 2; ++n) {
            int row = wc + 32 + n * 16 + fr;
#pragma unroll
            for (int ks = 0; ks < 2; ++ks) {
                int kc = ks * 4 + kq;
                bg1[n][ks] = *(const bf16x8*)(pB + row * BK + ((kc ^ (row & 7)) << 3));
            }
        }
        __builtin_amdgcn_s_setprio(1);
#pragma unroll
        for (int m = 0; m < 4; ++m)
#pragma unroll
            for (int n = 0; n < 2; ++n)
#pragma unroll
                for (int ks = 0; ks < 2; ++ks)
                    acc[m][n + 2] = __builtin_amdgcn_mfma_f32_16x16x32_bf16(
                        af0[m][ks], bg1[n][ks], acc[m][n + 2], 0, 0, 0);
        __builtin_amdgcn_s_setprio(0);
        asm volatile("s_barrier" ::: "memory");

        // ---- ph2: read af1 (8); MFMA q(1,1) = af1 x bg1; BAR ----
#pragma unroll
        for (int m = 0; m < 4; ++m) {
            int row = wr + 64 + m * 16 + fr;
#pragma unroll
            for (int ks = 0; ks < 2; ++ks) {
                int kc = ks * 4 + kq;
                af1[m][ks] = *(const bf16x8*)(pA + row * BK + ((kc ^ (row & 7)) << 3));
            }
        }
        __builtin_amdgcn_s_setprio(1);
#pragma unroll
        for (int m = 0; m < 4; ++m)
#pragma unroll
            for (int n = 0; n < 2; ++n)
#pragma unroll
                for (int ks = 0; ks < 2; ++ks)
                    acc[m + 4][n + 2] = __builtin_amdgcn_mfma_f32_16x16x32_bf16(
                        af1[m][ks], bg1[n][ks], acc[m + 4][n + 2], 0, 0, 0);
        __builtin_amdgcn_s_setprio(0);
        asm volatile("s_barrier" ::: "memory");
        // (ph2 barrier also protects buf[cur] reads from next iter's overwrites)

        // ---- ph3: no reads; MFMA q(1,0) = af1 x bg0 (bg0 held) ----
        __builtin_amdgcn_s_setprio(1);
#pragma unroll
        for (int m = 0; m < 4; ++m)
#pragma unroll
            for (int n = 0; n < 2; ++n)
#pragma unroll
                for (int ks = 0; ks < 2; ++ks)
                    acc[m + 4][n] = __builtin_amdgcn_mfma_f32_16x16x32_bf16(
                        af1[m][ks], bg0[n][ks], acc[m + 4][n], 0, 0, 0);
        __builtin_amdgcn_s_setprio(0);
    }

    // ---- epilogue: C/D layout col=lane&15, row=(lane>>4)*4+j ----
    const int crow = (lane >> 4) << 2;
    const int ccol = lane & 15;
#pragma unroll
    for (int m = 0; m < 8; ++m) {
#pragma unroll
        for (int n = 0; n < 4; ++n) {
            int col = col0 + wc + n * 16 + ccol;
            float b = bias[col];
#pragma unroll
            for (int j = 0; j < 4; ++j) {
                int row = row0 + wr + m * 16 + crow + j;
                out[(size_t)row * N_DIM + col] = acc[m][n][j] + b;
            }
        }
    }
}

// ---------------- Fallback: fused kernel (if ws too small) ----------------
#define FBM 128
#define FBN 128
#define FTHREADS 256
__global__ __launch_bounds__(FTHREADS) void dq_gemm_fused_kernel(
    const float* __restrict__ x, const int* __restrict__ wq,
    const float* __restrict__ scales, const float* __restrict__ bias,
    float* __restrict__ out)
{
    __shared__ bf16_t fA[FBM * BK];
    __shared__ bf16_t fB[FBN * BK];

    const int tid  = threadIdx.x;
    const int bm   = blockIdx.x / (N_DIM / FBN);
    const int bn   = blockIdx.x % (N_DIM / FBN);
    const int row0 = bm * FBM;
    const int col0 = bn * FBN;
    const int lane = tid & 63;
    const int wid  = tid >> 6;
    const int wr   = (wid >> 1) * 64;
    const int wc   = (wid & 1) * 64;
    const int fr   = lane & 15;
    const int fk   = (lane >> 4) << 3;

    f32x4 acc[4][4];
#pragma unroll
    for (int m = 0; m < 4; ++m)
#pragma unroll
        for (int n = 0; n < 4; ++n) acc[m][n] = (f32x4)0.f;

    for (int kt = 0; kt < K_DIM / BK; ++kt) {
        const int kb = kt * BK;
#pragma unroll
        for (int c = 0; c < 4; ++c) {
            int i  = c * FTHREADS + tid;
            int r  = i >> 3;
            int k0 = (i & 7) << 3;
            const float* gp = x + (size_t)(row0 + r) * K_DIM + kb + k0;
            f32x4 f0 = *(const f32x4*)gp;
            f32x4 f1 = *(const f32x4*)(gp + 4);
            bf16x8 v;
            v[0] = (bf16_t)f0[0]; v[1] = (bf16_t)f0[1];
            v[2] = (bf16_t)f0[2]; v[3] = (bf16_t)f0[3];
            v[4] = (bf16_t)f1[0]; v[5] = (bf16_t)f1[1];
            v[6] = (bf16_t)f1[2]; v[7] = (bf16_t)f1[3];
            *(bf16x8*)&fA[r * BK + (k0 ^ ((r & 7) << 3))] = v;
        }
#pragma unroll
        for (int c = 0; c < 4; ++c) {
            int i  = c * FTHREADS + tid;
            int r  = i >> 3;
            int k0 = (i & 7) << 3;
            int o  = col0 + r;
            const int* gq = wq + (size_t)o * K_DIM + kb + k0;
            i32x4 q0 = *(const i32x4*)gq;
            i32x4 q1 = *(const i32x4*)(gq + 4);
            float s = scales[o * NBLK + ((kb + k0) >> 5)];
            bf16x8 v;
            v[0] = (bf16_t)((float)q0[0] * s); v[1] = (bf16_t)((float)q0[1] * s);
            v[2] = (bf16_t)((float)q0[2] * s); v[3] = (bf16_t)((float)q0[3] * s);
            v[4] = (bf16_t)((float)q1[0] * s); v[5] = (bf16_t)((float)q1[1] * s);
            v[6] = (bf16_t)((float)q1[2] * s); v[7] = (bf16_t)((float)q1[3] * s);
            *(bf16x8*)&fB[r * BK + (k0 ^ ((r & 7) << 3))] = v;
        }
        __syncthreads();
#pragma unroll
        for (int ks = 0; ks < 2; ++ks) {
            bf16x8 af[4], bg[4];
#pragma unroll
            for (int m = 0; m < 4; ++m) {
                int r = wr + m * 16 + fr;
                af[m] = *(const bf16x8*)&fA[r * BK + ((ks * 32 + fk) ^ ((r & 7) << 3))];
            }
#pragma unroll
            for (int n = 0; n < 4; ++n) {
                int r = wc + n * 16 + fr;
                bg[n] = *(const bf16x8*)&fB[r * BK + ((ks * 32 + fk) ^ ((r & 7) << 3))];
            }
#pragma unroll
            for (int m = 0; m < 4; ++m)
#pragma unroll
                for (int n = 0; n < 4; ++n)
                    acc[m][n] = __builtin_amdgcn_mfma_f32_16x16x32_bf16(
                        af[m], bg[n], acc[m][n], 0, 0, 0);
        }
        __syncthreads();
    }

    const int crow = (lane >> 4) << 2;
    const int ccol = lane & 15;
#pragma unroll
    for (int m = 0; m < 4; ++m) {
#pragma unroll
        for (int n = 0; n < 4; ++n) {
            int col = col0 + wc + n * 16 + ccol;
            float b = bias[col];
#pragma unroll
            for (int j = 0; j < 4; ++j) {
                int row = row0 + wr + m * 16 + crow + j;
                out[(size_t)row * N_DIM + col] = acc[m][n][j] + b;
            }
        }
    }
}

extern "C" void kernel_launch(void* const* d_in, const int* in_sizes, int n_in,
                              void* d_out, int out_size, void* d_ws, size_t ws_size,
                              hipStream_t stream) {
    const float* x      = (const float*)d_in[0];
    const int*   wq     = (const int*)d_in[1];
    const float* scales = (const float*)d_in[2];
    const float* bias   = (const float*)d_in[3];
    float*       out    = (float*)d_out;

    if (ws_size >= W_BYTES + X_BYTES) {
        bf16_t* W = (bf16_t*)d_ws;
        bf16_t* X = (bf16_t*)((char*)d_ws + W_BYTES);
        dequant_w_kernel<<<dim3(N_DIM * K_DIM / 8 / 256), dim3(256), 0, stream>>>(wq, scales, W);
        cvt_x_kernel<<<dim3(M_DIM * K_DIM / 8 / 256), dim3(256), 0, stream>>>(x, X);
        gemm256_kernel<<<dim3((M_DIM / BM) * (N_DIM / BN)), dim3(THREADS), 0, stream>>>(X, W, bias, out);
    } else {
        dq_gemm_fused_kernel<<<dim3((M_DIM / FBM) * (N_DIM / FBN)), dim3(FTHREADS), 0, stream>>>(
            x, wq, scales, bias, out);
    }
}

// Round 6
// 349.469 us; speedup vs baseline: 1.4894x; 1.0543x over previous
//
#include <hip/hip_runtime.h>
#include <hip/hip_bf16.h>

typedef __bf16 bf16_t;
typedef __bf16 bf16x8 __attribute__((ext_vector_type(8)));
typedef float  f32x4  __attribute__((ext_vector_type(4)));
typedef int    i32x4  __attribute__((ext_vector_type(4)));

#define M_DIM 4096
#define N_DIM 12288
#define K_DIM 3072
#define NBLK  96      // K_DIM / 32 quant blocks per output row

#define BM 256
#define BN 256
#define BK 64
#define THREADS 512
#define NT (K_DIM / BK)   // 48 K-tiles

// ws layout: W_bf16 [N][K] at 0 (75.5 MB), X_bf16 [M][K] after (25.2 MB)
#define W_BYTES ((size_t)N_DIM * K_DIM * 2)
#define X_BYTES ((size_t)M_DIM * K_DIM * 2)

#define BAR()    asm volatile("s_barrier" ::: "memory")
#define LGKM0()  do { asm volatile("s_waitcnt lgkmcnt(0)" ::: "memory"); \
                      __builtin_amdgcn_sched_barrier(0); } while (0)

__device__ __forceinline__ void gload_lds16(const void* g, void* l) {
    // async global->LDS, 16B/lane; LDS dest = wave-uniform base + lane*16
    __builtin_amdgcn_global_load_lds(
        (const __attribute__((address_space(1))) unsigned int*)g,
        (__attribute__((address_space(3))) unsigned int*)l, 16, 0, 0);
}

// ---------------- Pass 1a: dequant Q8_0 weights -> bf16 ----------------
__global__ __launch_bounds__(256) void dequant_w_kernel(
    const int* __restrict__ wq, const float* __restrict__ scales,
    bf16_t* __restrict__ W)
{
    unsigned c = blockIdx.x * 256u + threadIdx.x;   // 8-elem chunk id
    unsigned o  = c / 384u;                         // 384 chunks per row
    unsigned kc = c - o * 384u;
    float s = scales[o * NBLK + (kc >> 2)];
    const int* gq = wq + (size_t)c * 8;
    i32x4 q0 = *(const i32x4*)gq;
    i32x4 q1 = *(const i32x4*)(gq + 4);
    bf16x8 v;
    v[0] = (bf16_t)((float)q0[0] * s); v[1] = (bf16_t)((float)q0[1] * s);
    v[2] = (bf16_t)((float)q0[2] * s); v[3] = (bf16_t)((float)q0[3] * s);
    v[4] = (bf16_t)((float)q1[0] * s); v[5] = (bf16_t)((float)q1[1] * s);
    v[6] = (bf16_t)((float)q1[2] * s); v[7] = (bf16_t)((float)q1[3] * s);
    *(bf16x8*)&W[(size_t)c * 8] = v;
}

// ---------------- Pass 1b: x fp32 -> bf16 ----------------
__global__ __launch_bounds__(256) void cvt_x_kernel(
    const float* __restrict__ x, bf16_t* __restrict__ X)
{
    unsigned c = blockIdx.x * 256u + threadIdx.x;
    const float* gp = x + (size_t)c * 8;
    f32x4 f0 = *(const f32x4*)gp;
    f32x4 f1 = *(const f32x4*)(gp + 4);
    bf16x8 v;
    v[0] = (bf16_t)f0[0]; v[1] = (bf16_t)f0[1];
    v[2] = (bf16_t)f0[2]; v[3] = (bf16_t)f0[3];
    v[4] = (bf16_t)f1[0]; v[5] = (bf16_t)f1[1];
    v[6] = (bf16_t)f1[2]; v[7] = (bf16_t)f1[3];
    *(bf16x8*)&X[(size_t)c * 8] = v;
}

// ---------------- Pass 2: fine-grained 4-phase pipelined bf16 GEMM ----------
// C[t][o] = sum_k X[t][k] * W[o][k] + bias[o]
// Per K-tile t (dbuf=t&1), phases (quadrant order (0,0),(1,0),(1,1),(0,1)):
//  ph0: rd af0+bg0 (12) | stage Bu0(t+1)->dbuf^1 | BAR LGKM0 | 16 MFMA | BAR
//  ph1: rd af1     (8)  | stage Bu1(t+1)->dbuf^1 | BAR LGKM0 | 16 MFMA | BAR
//  ph2: rd bg1     (4)  | stage Au0(t+2)->dbuf   | BAR LGKM0 | 16 MFMA | BAR
//  ph3:                 | stage Au1(t+2)->dbuf   | BAR | 16 MFMA | vmcnt(4) BAR
// Safety: A of tile t fully consumed by ph1's LGKM0+BAR -> ph2/ph3 may
// overwrite dbuf's A with tile t+2. B of t-1 consumed by t-1.ph2 -> ph0/ph1
// overwrite dbuf^1's B with t+1. vmcnt(4) drains exactly tiles t+1's units,
// keeps Au(t+2)'s 4 loads in flight (T4: never 0; >=2 phases slack per load).
// Swizzle both-sides (rule #21): linear LDS chunk (row,c8) holds global chunk
// (row, c8^(row&7)) via pre-swizzled global source; reads XOR the same.
__global__ __launch_bounds__(THREADS, 2) void gemm256f_kernel(
    const bf16_t* __restrict__ A, const bf16_t* __restrict__ B,
    const float* __restrict__ bias, float* __restrict__ out)
{
    __shared__ __align__(16) bf16_t sA[2][BM * BK];   // 2 x 32 KB
    __shared__ __align__(16) bf16_t sB[2][BN * BK];   // 2 x 32 KB -> 128 KB

    const int tid  = threadIdx.x;
    const int bm   = blockIdx.x / (N_DIM / BN);
    const int bn   = blockIdx.x % (N_DIM / BN);
    const int row0 = bm * BM;
    const int col0 = bn * BN;

    const int lane = tid & 63;
    const int wid  = tid >> 6;          // 8 waves: 2 (M) x 4 (N)
    const int wr   = (wid >> 2) * 128;  // wave row offset in tile
    const int wc   = (wid & 3) * 64;    // wave col offset in tile
    const int fr   = lane & 15;         // fragment row within 16
    const int kq   = lane >> 4;         // k-chunk quarter 0..3

    // staging: unit = 128 rows x 64 k (16 KB) = 2 issues/thread
    // issue j covers row = j*64 + (tid>>3), chunk c8 = tid&7 (pre-swizzled src)
    const int rws = tid >> 3;                         // 0..63
    const int c8s = (tid & 7) ^ (rws & 7);
    const bf16_t* srcA = A + (size_t)(row0 + rws) * K_DIM + c8s * 8;
    const bf16_t* srcB = B + (size_t)(col0 + rws) * K_DIM + c8s * 8;
    const int ldsU = (tid & ~63) * 8;                 // wave-uniform elem base

    auto stA = [&](int d, int uh, int tt) {
        const bf16_t* s = srcA + (size_t)tt * BK + (size_t)uh * 128 * K_DIM;
        gload_lds16(s,                        &sA[d][uh * 8192 + ldsU]);
        gload_lds16(s + (size_t)64 * K_DIM,   &sA[d][uh * 8192 + 4096 + ldsU]);
    };
    auto stB = [&](int d, int uh, int tt) {
        const bf16_t* s = srcB + (size_t)tt * BK + (size_t)uh * 128 * K_DIM;
        gload_lds16(s,                        &sB[d][uh * 8192 + ldsU]);
        gload_lds16(s + (size_t)64 * K_DIM,   &sB[d][uh * 8192 + 4096 + ldsU]);
    };

    f32x4 acc[8][4];
#pragma unroll
    for (int m = 0; m < 8; ++m)
#pragma unroll
        for (int n = 0; n < 4; ++n) acc[m][n] = (f32x4)0.f;

    auto rdA = [&](const bf16_t* pA, int rbase, bf16x8 (&dst)[4][2]) {
#pragma unroll
        for (int m = 0; m < 4; ++m) {
            int row = rbase + m * 16 + fr;
#pragma unroll
            for (int ks = 0; ks < 2; ++ks) {
                int kc = ks * 4 + kq;
                dst[m][ks] = *(const bf16x8*)(pA + row * BK + ((kc ^ (row & 7)) << 3));
            }
        }
    };
    auto rdB = [&](const bf16_t* pB, int rbase, bf16x8 (&dst)[2][2]) {
#pragma unroll
        for (int n = 0; n < 2; ++n) {
            int row = rbase + n * 16 + fr;
#pragma unroll
            for (int ks = 0; ks < 2; ++ks) {
                int kc = ks * 4 + kq;
                dst[n][ks] = *(const bf16x8*)(pB + row * BK + ((kc ^ (row & 7)) << 3));
            }
        }
    };
    auto mm = [&](bf16x8 (&a)[4][2], bf16x8 (&b)[2][2], int mo, int no) {
        __builtin_amdgcn_s_setprio(1);
#pragma unroll
        for (int m = 0; m < 4; ++m)
#pragma unroll
            for (int n = 0; n < 2; ++n)
#pragma unroll
                for (int ks = 0; ks < 2; ++ks)
                    acc[mo + m][no + n] = __builtin_amdgcn_mfma_f32_16x16x32_bf16(
                        a[m][ks], b[n][ks], acc[mo + m][no + n], 0, 0, 0);
        __builtin_amdgcn_s_setprio(0);
    };

    // ---- prologue: tile0 all 4 units + tile1 A units; drain tile0 only ----
    stA(0, 0, 0); stA(0, 1, 0); stB(0, 0, 0); stB(0, 1, 0);
    stA(1, 0, 1); stA(1, 1, 1);
    asm volatile("s_waitcnt vmcnt(4)" ::: "memory");
    BAR();

    auto ktile = [&](int cur, int t) {
        const bf16_t* pA = &sA[cur][0];
        const bf16_t* pB = &sB[cur][0];
        int t1 = t + 1; if (t1 >= NT) t1 -= NT;   // tail: dummy wrap refetch
        int t2 = t + 2; if (t2 >= NT) t2 -= NT;

        bf16x8 af0[4][2], af1[4][2], bg0[2][2], bg1[2][2];

        // ph0: q(0,0)
        rdA(pA, wr, af0); rdB(pB, wc, bg0);
        stB(cur ^ 1, 0, t1);
        BAR(); LGKM0();
        mm(af0, bg0, 0, 0);
        BAR();

        // ph1: q(1,0)
        rdA(pA, wr + 64, af1);
        stB(cur ^ 1, 1, t1);
        BAR(); LGKM0();
        mm(af1, bg0, 4, 0);
        BAR();

        // ph2: q(1,1)
        rdB(pB, wc + 32, bg1);
        stA(cur, 0, t2);
        BAR(); LGKM0();
        mm(af1, bg1, 4, 2);
        BAR();

        // ph3: q(0,1)
        stA(cur, 1, t2);
        BAR();
        __builtin_amdgcn_sched_barrier(0);
        mm(af0, bg1, 0, 2);
        __builtin_amdgcn_sched_barrier(0);
        asm volatile("s_waitcnt vmcnt(4)" ::: "memory");
        BAR();
    };

    for (int it = 0; it < NT / 2; ++it) {
        ktile(0, it * 2);
        ktile(1, it * 2 + 1);
    }

    // ---- epilogue: C/D layout col=lane&15, row=(lane>>4)*4+j ----
    const int crow = (lane >> 4) << 2;
    const int ccol = lane & 15;
#pragma unroll
    for (int m = 0; m < 8; ++m) {
#pragma unroll
        for (int n = 0; n < 4; ++n) {
            int col = col0 + wc + n * 16 + ccol;
            float b = bias[col];
#pragma unroll
            for (int j = 0; j < 4; ++j) {
                int row = row0 + wr + m * 16 + crow + j;
                out[(size_t)row * N_DIM + col] = acc[m][n][j] + b;
            }
        }
    }
}

// ---------------- Fallback: fused kernel (if ws too small) ----------------
#define FBM 128
#define FBN 128
#define FTHREADS 256
__global__ __launch_bounds__(FTHREADS) void dq_gemm_fused_kernel(
    const float* __restrict__ x, const int* __restrict__ wq,
    const float* __restrict__ scales, const float* __restrict__ bias,
    float* __restrict__ out)
{
    __shared__ bf16_t fA[FBM * BK];
    __shared__ bf16_t fB[FBN * BK];

    const int tid  = threadIdx.x;
    const int bm   = blockIdx.x / (N_DIM / FBN);
    const int bn   = blockIdx.x % (N_DIM / FBN);
    const int row0 = bm * FBM;
    const int col0 = bn * FBN;
    const int lane = tid & 63;
    const int wid  = tid >> 6;
    const int wr   = (wid >> 1) * 64;
    const int wc   = (wid & 1) * 64;
    const int fr   = lane & 15;
    const int fk   = (lane >> 4) << 3;

    f32x4 acc[4][4];
#pragma unroll
    for (int m = 0; m < 4; ++m)
#pragma unroll
        for (int n = 0; n < 4; ++n) acc[m][n] = (f32x4)0.f;

    for (int kt = 0; kt < K_DIM / BK; ++kt) {
        const int kb = kt * BK;
#pragma unroll
        for (int c = 0; c < 4; ++c) {
            int i  = c * FTHREADS + tid;
            int r  = i >> 3;
            int k0 = (i & 7) << 3;
            const float* gp = x + (size_t)(row0 + r) * K_DIM + kb + k0;
            f32x4 f0 = *(const f32x4*)gp;
            f32x4 f1 = *(const f32x4*)(gp + 4);
            bf16x8 v;
            v[0] = (bf16_t)f0[0]; v[1] = (bf16_t)f0[1];
            v[2] = (bf16_t)f0[2]; v[3] = (bf16_t)f0[3];
            v[4] = (bf16_t)f1[0]; v[5] = (bf16_t)f1[1];
            v[6] = (bf16_t)f1[2]; v[7] = (bf16_t)f1[3];
            *(bf16x8*)&fA[r * BK + (k0 ^ ((r & 7) << 3))] = v;
        }
#pragma unroll
        for (int c = 0; c < 4; ++c) {
            int i  = c * FTHREADS + tid;
            int r  = i >> 3;
            int k0 = (i & 7) << 3;
            int o  = col0 + r;
            const int* gq = wq + (size_t)o * K_DIM + kb + k0;
            i32x4 q0 = *(const i32x4*)gq;
            i32x4 q1 = *(const i32x4*)(gq + 4);
            float s = scales[o * NBLK + ((kb + k0) >> 5)];
            bf16x8 v;
            v[0] = (bf16_t)((float)q0[0] * s); v[1] = (bf16_t)((float)q0[1] * s);
            v[2] = (bf16_t)((float)q0[2] * s); v[3] = (bf16_t)((float)q0[3] * s);
            v[4] = (bf16_t)((float)q1[0] * s); v[5] = (bf16_t)((float)q1[1] * s);
            v[6] = (bf16_t)((float)q1[2] * s); v[7] = (bf16_t)((float)q1[3] * s);
            *(bf16x8*)&fB[r * BK + (k0 ^ ((r & 7) << 3))] = v;
        }
        __syncthreads();
#pragma unroll
        for (int ks = 0; ks < 2; ++ks) {
            bf16x8 af[4], bg[4];
#pragma unroll
            for (int m = 0; m < 4; ++m) {
                int r = wr + m * 16 + fr;
                af[m] = *(const bf16x8*)&fA[r * BK + ((ks * 32 + fk) ^ ((r & 7) << 3))];
            }
#pragma unroll
            for (int n = 0; n < 4; ++n) {
                int r = wc + n * 16 + fr;
                bg[n] = *(const bf16x8*)&fB[r * BK + ((ks * 32 + fk) ^ ((r & 7) << 3))];
            }
#pragma unroll
            for (int m = 0; m < 4; ++m)
#pragma unroll
                for (int n = 0; n < 4; ++n)
                    acc[m][n] = __builtin_amdgcn_mfma_f32_16x16x32_bf16(
                        af[m], bg[n], acc[m][n], 0, 0, 0);
        }
        __syncthreads();
    }

    const int crow = (lane >> 4) << 2;
    const int ccol = lane & 15;
#pragma unroll
    for (int m = 0; m < 4; ++m) {
#pragma unroll
        for (int n = 0; n < 4; ++n) {
            int col = col0 + wc + n * 16 + ccol;
            float b = bias[col];
#pragma unroll
            for (int j = 0; j < 4; ++j) {
                int row = row0 + wr + m * 16 + crow + j;
                out[(size_t)row * N_DIM + col] = acc[m][n][j] + b;
            }
        }
    }
}

extern "C" void kernel_launch(void* const* d_in, const int* in_sizes, int n_in,
                              void* d_out, int out_size, void* d_ws, size_t ws_size,
                              hipStream_t stream) {
    const float* x      = (const float*)d_in[0];
    const int*   wq     = (const int*)d_in[1];
    const float* scales = (const float*)d_in[2];
    const float* bias   = (const float*)d_in[3];
    float*       out    = (float*)d_out;

    if (ws_size >= W_BYTES + X_BYTES) {
        bf16_t* W = (bf16_t*)d_ws;
        bf16_t* X = (bf16_t*)((char*)d_ws + W_BYTES);
        dequant_w_kernel<<<dim3(N_DIM * K_DIM / 8 / 256), dim3(256), 0, stream>>>(wq, scales, W);
        cvt_x_kernel<<<dim3(M_DIM * K_DIM / 8 / 256), dim3(256), 0, stream>>>(x, X);
        gemm256f_kernel<<<dim3((M_DIM / BM) * (N_DIM / BN)), dim3(THREADS), 0, stream>>>(X, W, bias, out);
    } else {
        dq_gemm_fused_kernel<<<dim3((M_DIM / FBM) * (N_DIM / FBN)), dim3(FTHREADS), 0, stream>>>(
            x, wq, scales, bias, out);
    }
}

// Round 7
// 334.590 us; speedup vs baseline: 1.5556x; 1.0445x over previous
//
#include <hip/hip_runtime.h>
#include <hip/hip_bf16.h>

typedef __bf16 bf16_t;
typedef __bf16 bf16x8 __attribute__((ext_vector_type(8)));
typedef float  f32x4  __attribute__((ext_vector_type(4)));
typedef int    i32x4  __attribute__((ext_vector_type(4)));

#define M_DIM 4096
#define N_DIM 12288
#define K_DIM 3072
#define NBLK  96      // K_DIM / 32 quant blocks per output row

#define BM 256
#define BN 256
#define BK 64
#define THREADS 512
#define NT (K_DIM / BK)   // 48 K-tiles

// ws layout: W_bf16 [N][K] at 0 (75.5 MB), X_bf16 [M][K] after (25.2 MB)
#define W_BYTES ((size_t)N_DIM * K_DIM * 2)
#define X_BYTES ((size_t)M_DIM * K_DIM * 2)

#define BAR()   asm volatile("s_barrier" ::: "memory")
#define SBAR()  __builtin_amdgcn_sched_barrier(0)

__device__ __forceinline__ void gload_lds16(const void* g, void* l) {
    // async global->LDS, 16B/lane; LDS dest = wave-uniform base + lane*16
    __builtin_amdgcn_global_load_lds(
        (const __attribute__((address_space(1))) unsigned int*)g,
        (__attribute__((address_space(3))) unsigned int*)l, 16, 0, 0);
}

// ---------------- Pass 1a: dequant Q8_0 weights -> bf16 ----------------
__global__ __launch_bounds__(256) void dequant_w_kernel(
    const int* __restrict__ wq, const float* __restrict__ scales,
    bf16_t* __restrict__ W)
{
    unsigned c = blockIdx.x * 256u + threadIdx.x;   // 8-elem chunk id
    unsigned o  = c / 384u;                         // 384 chunks per row
    unsigned kc = c - o * 384u;
    float s = scales[o * NBLK + (kc >> 2)];
    const int* gq = wq + (size_t)c * 8;
    i32x4 q0 = *(const i32x4*)gq;
    i32x4 q1 = *(const i32x4*)(gq + 4);
    bf16x8 v;
    v[0] = (bf16_t)((float)q0[0] * s); v[1] = (bf16_t)((float)q0[1] * s);
    v[2] = (bf16_t)((float)q0[2] * s); v[3] = (bf16_t)((float)q0[3] * s);
    v[4] = (bf16_t)((float)q1[0] * s); v[5] = (bf16_t)((float)q1[1] * s);
    v[6] = (bf16_t)((float)q1[2] * s); v[7] = (bf16_t)((float)q1[3] * s);
    *(bf16x8*)&W[(size_t)c * 8] = v;
}

// ---------------- Pass 1b: x fp32 -> bf16 ----------------
__global__ __launch_bounds__(256) void cvt_x_kernel(
    const float* __restrict__ x, bf16_t* __restrict__ X)
{
    unsigned c = blockIdx.x * 256u + threadIdx.x;
    const float* gp = x + (size_t)c * 8;
    f32x4 f0 = *(const f32x4*)gp;
    f32x4 f1 = *(const f32x4*)(gp + 4);
    bf16x8 v;
    v[0] = (bf16_t)f0[0]; v[1] = (bf16_t)f0[1];
    v[2] = (bf16_t)f0[2]; v[3] = (bf16_t)f0[3];
    v[4] = (bf16_t)f1[0]; v[5] = (bf16_t)f1[1];
    v[6] = (bf16_t)f1[2]; v[7] = (bf16_t)f1[3];
    *(bf16x8*)&X[(size_t)c * 8] = v;
}

// ---------------- Pass 2: read-ahead 4-phase pipelined bf16 GEMM ------------
// C[t][o] = sum_k X[t][k] * W[o][k] + bias[o]
// Per K-tile t (dbuf=t&1): ALL 24 fragment ds_reads issued up front (order
// pinned af0,bg0 | af1 | bg1). Compiler's precise waitcnt gives partial
// drains: lgkmcnt(12) before q00, (4) before q10, (0) before q11 -> af1/bg1
// drain UNDER the q00/q10 MFMA bursts (m201's read-ahead mechanism).
// Staging unchanged (units): Bu0,Bu1(t+1)->dbuf^1 in ph0/ph1; Au0,Au1(t+2)
// ->dbuf in ph2/ph3 (A of t consumed into regs by then). vmcnt(4) at tile
// end drains exactly t+1's units, keeps Au(t+2) in flight (T4: never 0).
// Swizzle both-sides (rule #21): linear LDS chunk (row,c8) holds global chunk
// (row, c8^(row&7)) via pre-swizzled global source; reads XOR the same.
__global__ __launch_bounds__(THREADS, 2) void gemm256r_kernel(
    const bf16_t* __restrict__ A, const bf16_t* __restrict__ B,
    const float* __restrict__ bias, float* __restrict__ out)
{
    __shared__ __align__(16) bf16_t sA[2][BM * BK];   // 2 x 32 KB
    __shared__ __align__(16) bf16_t sB[2][BN * BK];   // 2 x 32 KB -> 128 KB

    const int tid  = threadIdx.x;
    const int bm   = blockIdx.x / (N_DIM / BN);
    const int bn   = blockIdx.x % (N_DIM / BN);
    const int row0 = bm * BM;
    const int col0 = bn * BN;

    const int lane = tid & 63;
    const int wid  = tid >> 6;          // 8 waves: 2 (M) x 4 (N)
    const int wr   = (wid >> 2) * 128;  // wave row offset in tile
    const int wc   = (wid & 3) * 64;    // wave col offset in tile
    const int fr   = lane & 15;         // fragment row within 16
    const int kq   = lane >> 4;         // k-chunk quarter 0..3

    // staging: unit = 128 rows x 64 k (16 KB) = 2 issues/thread
    const int rws = tid >> 3;                         // 0..63
    const int c8s = (tid & 7) ^ (rws & 7);
    const bf16_t* srcA = A + (size_t)(row0 + rws) * K_DIM + c8s * 8;
    const bf16_t* srcB = B + (size_t)(col0 + rws) * K_DIM + c8s * 8;
    const int ldsU = (tid & ~63) * 8;                 // wave-uniform elem base

    auto stA = [&](int d, int uh, int tt) {
        const bf16_t* s = srcA + (size_t)tt * BK + (size_t)uh * 128 * K_DIM;
        gload_lds16(s,                        &sA[d][uh * 8192 + ldsU]);
        gload_lds16(s + (size_t)64 * K_DIM,   &sA[d][uh * 8192 + 4096 + ldsU]);
    };
    auto stB = [&](int d, int uh, int tt) {
        const bf16_t* s = srcB + (size_t)tt * BK + (size_t)uh * 128 * K_DIM;
        gload_lds16(s,                        &sB[d][uh * 8192 + ldsU]);
        gload_lds16(s + (size_t)64 * K_DIM,   &sB[d][uh * 8192 + 4096 + ldsU]);
    };

    f32x4 acc[8][4];
#pragma unroll
    for (int m = 0; m < 8; ++m)
#pragma unroll
        for (int n = 0; n < 4; ++n) acc[m][n] = (f32x4)0.f;

    auto rdA = [&](const bf16_t* pA, int rbase, bf16x8 (&dst)[4][2]) {
#pragma unroll
        for (int m = 0; m < 4; ++m) {
            int row = rbase + m * 16 + fr;
#pragma unroll
            for (int ks = 0; ks < 2; ++ks) {
                int kc = ks * 4 + kq;
                dst[m][ks] = *(const bf16x8*)(pA + row * BK + ((kc ^ (row & 7)) << 3));
            }
        }
    };
    auto rdB = [&](const bf16_t* pB, int rbase, bf16x8 (&dst)[2][2]) {
#pragma unroll
        for (int n = 0; n < 2; ++n) {
            int row = rbase + n * 16 + fr;
#pragma unroll
            for (int ks = 0; ks < 2; ++ks) {
                int kc = ks * 4 + kq;
                dst[n][ks] = *(const bf16x8*)(pB + row * BK + ((kc ^ (row & 7)) << 3));
            }
        }
    };
    auto mm = [&](bf16x8 (&a)[4][2], bf16x8 (&b)[2][2], int mo, int no) {
        __builtin_amdgcn_s_setprio(1);
#pragma unroll
        for (int m = 0; m < 4; ++m)
#pragma unroll
            for (int n = 0; n < 2; ++n)
#pragma unroll
                for (int ks = 0; ks < 2; ++ks)
                    acc[mo + m][no + n] = __builtin_amdgcn_mfma_f32_16x16x32_bf16(
                        a[m][ks], b[n][ks], acc[mo + m][no + n], 0, 0, 0);
        __builtin_amdgcn_s_setprio(0);
    };

    // ---- prologue: tile0 all 4 units + tile1 A units; drain tile0 only ----
    stA(0, 0, 0); stA(0, 1, 0); stB(0, 0, 0); stB(0, 1, 0);
    stA(1, 0, 1); stA(1, 1, 1);
    asm volatile("s_waitcnt vmcnt(4)" ::: "memory");
    BAR();

    auto ktile = [&](int cur, int t) {
        const bf16_t* pA = &sA[cur][0];
        const bf16_t* pB = &sB[cur][0];
        int t1 = t + 1; if (t1 >= NT) t1 -= NT;   // tail: dummy wrap refetch
        int t2 = t + 2; if (t2 >= NT) t2 -= NT;

        bf16x8 af0[4][2], af1[4][2], bg0[2][2], bg1[2][2];

        // ---- read window: all 24 ds_reads, order pinned oldest-first ----
        rdA(pA, wr, af0); rdB(pB, wc, bg0);   // 12 (needed by q00)
        SBAR();
        rdA(pA, wr + 64, af1);                // 8  (needed by q10)
        SBAR();
        rdB(pB, wc + 32, bg1);                // 4  (needed by q11)
        stB(cur ^ 1, 0, t1);
        BAR(); SBAR();
        mm(af0, bg0, 0, 0);                   // compiler: lgkmcnt(12)
        BAR();

        stB(cur ^ 1, 1, t1);
        BAR(); SBAR();
        mm(af1, bg0, 4, 0);                   // compiler: lgkmcnt(4)
        BAR();

        stA(cur, 0, t2);
        BAR(); SBAR();
        mm(af1, bg1, 4, 2);                   // compiler: lgkmcnt(0)
        BAR();

        stA(cur, 1, t2);
        BAR(); SBAR();
        mm(af0, bg1, 0, 2);
        SBAR();
        asm volatile("s_waitcnt vmcnt(4)" ::: "memory");
        BAR();
    };

    for (int it = 0; it < NT / 2; ++it) {
        ktile(0, it * 2);
        ktile(1, it * 2 + 1);
    }

    // ---- epilogue: C/D layout col=lane&15, row=(lane>>4)*4+j ----
    const int crow = (lane >> 4) << 2;
    const int ccol = lane & 15;
#pragma unroll
    for (int m = 0; m < 8; ++m) {
#pragma unroll
        for (int n = 0; n < 4; ++n) {
            int col = col0 + wc + n * 16 + ccol;
            float b = bias[col];
#pragma unroll
            for (int j = 0; j < 4; ++j) {
                int row = row0 + wr + m * 16 + crow + j;
                out[(size_t)row * N_DIM + col] = acc[m][n][j] + b;
            }
        }
    }
}

// ---------------- Fallback: fused kernel (if ws too small) ----------------
#define FBM 128
#define FBN 128
#define FTHREADS 256
__global__ __launch_bounds__(FTHREADS) void dq_gemm_fused_kernel(
    const float* __restrict__ x, const int* __restrict__ wq,
    const float* __restrict__ scales, const float* __restrict__ bias,
    float* __restrict__ out)
{
    __shared__ bf16_t fA[FBM * BK];
    __shared__ bf16_t fB[FBN * BK];

    const int tid  = threadIdx.x;
    const int bm   = blockIdx.x / (N_DIM / FBN);
    const int bn   = blockIdx.x % (N_DIM / FBN);
    const int row0 = bm * FBM;
    const int col0 = bn * FBN;
    const int lane = tid & 63;
    const int wid  = tid >> 6;
    const int wr   = (wid >> 1) * 64;
    const int wc   = (wid & 1) * 64;
    const int fr   = lane & 15;
    const int fk   = (lane >> 4) << 3;

    f32x4 acc[4][4];
#pragma unroll
    for (int m = 0; m < 4; ++m)
#pragma unroll
        for (int n = 0; n < 4; ++n) acc[m][n] = (f32x4)0.f;

    for (int kt = 0; kt < K_DIM / BK; ++kt) {
        const int kb = kt * BK;
#pragma unroll
        for (int c = 0; c < 4; ++c) {
            int i  = c * FTHREADS + tid;
            int r  = i >> 3;
            int k0 = (i & 7) << 3;
            const float* gp = x + (size_t)(row0 + r) * K_DIM + kb + k0;
            f32x4 f0 = *(const f32x4*)gp;
            f32x4 f1 = *(const f32x4*)(gp + 4);
            bf16x8 v;
            v[0] = (bf16_t)f0[0]; v[1] = (bf16_t)f0[1];
            v[2] = (bf16_t)f0[2]; v[3] = (bf16_t)f0[3];
            v[4] = (bf16_t)f1[0]; v[5] = (bf16_t)f1[1];
            v[6] = (bf16_t)f1[2]; v[7] = (bf16_t)f1[3];
            *(bf16x8*)&fA[r * BK + (k0 ^ ((r & 7) << 3))] = v;
        }
#pragma unroll
        for (int c = 0; c < 4; ++c) {
            int i  = c * FTHREADS + tid;
            int r  = i >> 3;
            int k0 = (i & 7) << 3;
            int o  = col0 + r;
            const int* gq = wq + (size_t)o * K_DIM + kb + k0;
            i32x4 q0 = *(const i32x4*)gq;
            i32x4 q1 = *(const i32x4*)(gq + 4);
            float s = scales[o * NBLK + ((kb + k0) >> 5)];
            bf16x8 v;
            v[0] = (bf16_t)((float)q0[0] * s); v[1] = (bf16_t)((float)q0[1] * s);
            v[2] = (bf16_t)((float)q0[2] * s); v[3] = (bf16_t)((float)q0[3] * s);
            v[4] = (bf16_t)((float)q1[0] * s); v[5] = (bf16_t)((float)q1[1] * s);
            v[6] = (bf16_t)((float)q1[2] * s); v[7] = (bf16_t)((float)q1[3] * s);
            *(bf16x8*)&fB[r * BK + (k0 ^ ((r & 7) << 3))] = v;
        }
        __syncthreads();
#pragma unroll
        for (int ks = 0; ks < 2; ++ks) {
            bf16x8 af[4], bg[4];
#pragma unroll
            for (int m = 0; m < 4; ++m) {
                int r = wr + m * 16 + fr;
                af[m] = *(const bf16x8*)&fA[r * BK + ((ks * 32 + fk) ^ ((r & 7) << 3))];
            }
#pragma unroll
            for (int n = 0; n < 4; ++n) {
                int r = wc + n * 16 + fr;
                bg[n] = *(const bf16x8*)&fB[r * BK + ((ks * 32 + fk) ^ ((r & 7) << 3))];
            }
#pragma unroll
            for (int m = 0; m < 4; ++m)
#pragma unroll
                for (int n = 0; n < 4; ++n)
                    acc[m][n] = __builtin_amdgcn_mfma_f32_16x16x32_bf16(
                        af[m], bg[n], acc[m][n], 0, 0, 0);
        }
        __syncthreads();
    }

    const int crow = (lane >> 4) << 2;
    const int ccol = lane & 15;
#pragma unroll
    for (int m = 0; m < 4; ++m) {
#pragma unroll
        for (int n = 0; n < 4; ++n) {
            int col = col0 + wc + n * 16 + ccol;
            float b = bias[col];
#pragma unroll
            for (int j = 0; j < 4; ++j) {
                int row = row0 + wr + m * 16 + crow + j;
                out[(size_t)row * N_DIM + col] = acc[m][n][j] + b;
            }
        }
    }
}

extern "C" void kernel_launch(void* const* d_in, const int* in_sizes, int n_in,
                              void* d_out, int out_size, void* d_ws, size_t ws_size,
                              hipStream_t stream) {
    const float* x      = (const float*)d_in[0];
    const int*   wq     = (const int*)d_in[1];
    const float* scales = (const float*)d_in[2];
    const float* bias   = (const float*)d_in[3];
    float*       out    = (float*)d_out;

    if (ws_size >= W_BYTES + X_BYTES) {
        bf16_t* W = (bf16_t*)d_ws;
        bf16_t* X = (bf16_t*)((char*)d_ws + W_BYTES);
        dequant_w_kernel<<<dim3(N_DIM * K_DIM / 8 / 256), dim3(256), 0, stream>>>(wq, scales, W);
        cvt_x_kernel<<<dim3(M_DIM * K_DIM / 8 / 256), dim3(256), 0, stream>>>(x, X);
        gemm256r_kernel<<<dim3((M_DIM / BM) * (N_DIM / BN)), dim3(THREADS), 0, stream>>>(X, W, bias, out);
    } else {
        dq_gemm_fused_kernel<<<dim3((M_DIM / FBM) * (N_DIM / FBN)), dim3(FTHREADS), 0, stream>>>(
            x, wq, scales, bias, out);
    }
}

// Round 8
// 313.125 us; speedup vs baseline: 1.6622x; 1.0686x over previous
//
#include <hip/hip_runtime.h>
#include <hip/hip_bf16.h>

typedef __bf16 bf16_t;
typedef __bf16 bf16x8 __attribute__((ext_vector_type(8)));
typedef float  f32x4  __attribute__((ext_vector_type(4)));
typedef int    i32x4  __attribute__((ext_vector_type(4)));

#define M_DIM 4096
#define N_DIM 12288
#define K_DIM 3072
#define NBLK  96      // K_DIM / 32 quant blocks per output row

#define BM 256
#define BN 256
#define BK 64
#define THREADS 512
#define NT (K_DIM / BK)   // 48 K-tiles

// ws layout: W_bf16 [N][K] at 0 (75.5 MB), X_bf16 [M][K] after (25.2 MB)
#define W_BYTES ((size_t)N_DIM * K_DIM * 2)
#define X_BYTES ((size_t)M_DIM * K_DIM * 2)

#define BAR()   asm volatile("s_barrier" ::: "memory")
#define SBAR()  __builtin_amdgcn_sched_barrier(0)

__device__ __forceinline__ void gload_lds16(const void* g, void* l) {
    // async global->LDS, 16B/lane; LDS dest = wave-uniform base + lane*16
    __builtin_amdgcn_global_load_lds(
        (const __attribute__((address_space(1))) unsigned int*)g,
        (__attribute__((address_space(3))) unsigned int*)l, 16, 0, 0);
}

// ---------------- Pass 1a: dequant Q8_0 weights -> bf16 ----------------
__global__ __launch_bounds__(256) void dequant_w_kernel(
    const int* __restrict__ wq, const float* __restrict__ scales,
    bf16_t* __restrict__ W)
{
    unsigned c = blockIdx.x * 256u + threadIdx.x;   // 8-elem chunk id
    unsigned o  = c / 384u;                         // 384 chunks per row
    unsigned kc = c - o * 384u;
    float s = scales[o * NBLK + (kc >> 2)];
    const int* gq = wq + (size_t)c * 8;
    i32x4 q0 = *(const i32x4*)gq;
    i32x4 q1 = *(const i32x4*)(gq + 4);
    bf16x8 v;
    v[0] = (bf16_t)((float)q0[0] * s); v[1] = (bf16_t)((float)q0[1] * s);
    v[2] = (bf16_t)((float)q0[2] * s); v[3] = (bf16_t)((float)q0[3] * s);
    v[4] = (bf16_t)((float)q1[0] * s); v[5] = (bf16_t)((float)q1[1] * s);
    v[6] = (bf16_t)((float)q1[2] * s); v[7] = (bf16_t)((float)q1[3] * s);
    *(bf16x8*)&W[(size_t)c * 8] = v;
}

// ---------------- Pass 1b: x fp32 -> bf16 ----------------
__global__ __launch_bounds__(256) void cvt_x_kernel(
    const float* __restrict__ x, bf16_t* __restrict__ X)
{
    unsigned c = blockIdx.x * 256u + threadIdx.x;
    const float* gp = x + (size_t)c * 8;
    f32x4 f0 = *(const f32x4*)gp;
    f32x4 f1 = *(const f32x4*)(gp + 4);
    bf16x8 v;
    v[0] = (bf16_t)f0[0]; v[1] = (bf16_t)f0[1];
    v[2] = (bf16_t)f0[2]; v[3] = (bf16_t)f0[3];
    v[4] = (bf16_t)f1[0]; v[5] = (bf16_t)f1[1];
    v[6] = (bf16_t)f1[2]; v[7] = (bf16_t)f1[3];
    *(bf16x8*)&X[(size_t)c * 8] = v;
}

// ---------------- Pass 2: rotated-read pipelined bf16 GEMM ------------------
// C[t][o] = sum_k X[t][k] * W[o][k] + bias[o]
// Schedule per K-tile t (cur=t&1), 4 MFMA phases, reads rotated one phase
// ahead so every LDS drain hides under an MFMA burst:
//  phA: rd af1 (8)  | stB(nxt,u0,t+1) | q00 (af0,bg0 read in prev phD)
//  phB: rd bg1 (4)  | stB(nxt,u1,t+1) | q10             | BAR (protects stA)
//  phC: stA(cur,u0+u1,t+2)            | q11 | vmcnt(4)  | BAR (publish nxt)
//  phD: rd af0',bg0' (12) from buf[nxt]                 | q01 (regs only)
// 2 barriers/tile (was 8): end-B (A(cur) overwrite safety: all af reads
// drained before each wave's q10), end-C (vmcnt drains t+1's 8 units, keeps
// A(t+2)'s 4 in flight -> buf[nxt] valid for phD). Register banks alternate
// per tile (explicit 2-tile unroll, static indexing per rule #20).
// Swizzle both-sides (rule #21): linear LDS chunk (row,c8) holds global chunk
// (row, c8^(row&7)) via pre-swizzled global source; reads XOR the same.
__global__ __launch_bounds__(THREADS, 2) void gemm256p_kernel(
    const bf16_t* __restrict__ A, const bf16_t* __restrict__ B,
    const float* __restrict__ bias, float* __restrict__ out)
{
    __shared__ __align__(16) bf16_t sA[2][BM * BK];   // 2 x 32 KB
    __shared__ __align__(16) bf16_t sB[2][BN * BK];   // 2 x 32 KB -> 128 KB

    const int tid  = threadIdx.x;
    const int bm   = blockIdx.x / (N_DIM / BN);
    const int bn   = blockIdx.x % (N_DIM / BN);
    const int row0 = bm * BM;
    const int col0 = bn * BN;

    const int lane = tid & 63;
    const int wid  = tid >> 6;          // 8 waves: 2 (M) x 4 (N)
    const int wr   = (wid >> 2) * 128;  // wave row offset in tile
    const int wc   = (wid & 3) * 64;    // wave col offset in tile
    const int fr   = lane & 15;         // fragment row within 16
    const int kq   = lane >> 4;         // k-chunk quarter 0..3

    // staging: unit = 128 rows x 64 k (16 KB) = 2 issues/thread
    const int rws = tid >> 3;                         // 0..63
    const int c8s = (tid & 7) ^ (rws & 7);
    const bf16_t* srcA = A + (size_t)(row0 + rws) * K_DIM + c8s * 8;
    const bf16_t* srcB = B + (size_t)(col0 + rws) * K_DIM + c8s * 8;
    const int ldsU = (tid & ~63) * 8;                 // wave-uniform elem base

    auto stA = [&](int d, int uh, int tt) {
        const bf16_t* s = srcA + (size_t)tt * BK + (size_t)uh * 128 * K_DIM;
        gload_lds16(s,                        &sA[d][uh * 8192 + ldsU]);
        gload_lds16(s + (size_t)64 * K_DIM,   &sA[d][uh * 8192 + 4096 + ldsU]);
    };
    auto stB = [&](int d, int uh, int tt) {
        const bf16_t* s = srcB + (size_t)tt * BK + (size_t)uh * 128 * K_DIM;
        gload_lds16(s,                        &sB[d][uh * 8192 + ldsU]);
        gload_lds16(s + (size_t)64 * K_DIM,   &sB[d][uh * 8192 + 4096 + ldsU]);
    };

    f32x4 acc[8][4];
#pragma unroll
    for (int m = 0; m < 8; ++m)
#pragma unroll
        for (int n = 0; n < 4; ++n) acc[m][n] = (f32x4)0.f;

    auto rdA = [&](const bf16_t* pA, int rbase, bf16x8 (&dst)[4][2]) {
#pragma unroll
        for (int m = 0; m < 4; ++m) {
            int row = rbase + m * 16 + fr;
#pragma unroll
            for (int ks = 0; ks < 2; ++ks) {
                int kc = ks * 4 + kq;
                dst[m][ks] = *(const bf16x8*)(pA + row * BK + ((kc ^ (row & 7)) << 3));
            }
        }
    };
    auto rdB = [&](const bf16_t* pB, int rbase, bf16x8 (&dst)[2][2]) {
#pragma unroll
        for (int n = 0; n < 2; ++n) {
            int row = rbase + n * 16 + fr;
#pragma unroll
            for (int ks = 0; ks < 2; ++ks) {
                int kc = ks * 4 + kq;
                dst[n][ks] = *(const bf16x8*)(pB + row * BK + ((kc ^ (row & 7)) << 3));
            }
        }
    };
    auto mm = [&](bf16x8 (&a)[4][2], bf16x8 (&b)[2][2], int mo, int no) {
        __builtin_amdgcn_s_setprio(1);
#pragma unroll
        for (int m = 0; m < 4; ++m)
#pragma unroll
            for (int n = 0; n < 2; ++n)
#pragma unroll
                for (int ks = 0; ks < 2; ++ks)
                    acc[mo + m][no + n] = __builtin_amdgcn_mfma_f32_16x16x32_bf16(
                        a[m][ks], b[n][ks], acc[mo + m][no + n], 0, 0, 0);
        __builtin_amdgcn_s_setprio(0);
    };

    // register banks (alternate per tile; all static indexing)
    bf16x8 af0a[4][2], af1a[4][2], bg0a[2][2], bg1a[2][2];
    bf16x8 af0b[4][2], af1b[4][2], bg0b[2][2], bg1b[2][2];

    // ---- prologue: tile0 all units + tile1 A units; drain tile0; read 12 ----
    stA(0, 0, 0); stA(0, 1, 0); stB(0, 0, 0); stB(0, 1, 0);
    stA(1, 0, 1); stA(1, 1, 1);
    asm volatile("s_waitcnt vmcnt(4)" ::: "memory");
    BAR();
    rdA(&sA[0][0], wr, af0a); rdB(&sB[0][0], wc, bg0a);

    // ktile: runs phases A,B,C,D for tile t; reads next tile's af0/bg0 in phD
    auto ktile = [&](int cur, int t,
                     bf16x8 (&AF0)[4][2], bf16x8 (&AF1)[4][2],
                     bf16x8 (&BG0)[2][2], bf16x8 (&BG1)[2][2],
                     bf16x8 (&AF0n)[4][2], bf16x8 (&BG0n)[2][2]) {
        const bf16_t* pA = &sA[cur][0];
        const bf16_t* pB = &sB[cur][0];
        const bf16_t* pAn = &sA[cur ^ 1][0];
        const bf16_t* pBn = &sB[cur ^ 1][0];
        int t1 = t + 1; if (t1 >= NT) t1 -= NT;   // tail: dummy wrap refetch
        int t2 = t + 2; if (t2 >= NT) t2 -= NT;

        // phA: q00 | read af1 | stage B u0
        rdA(pA, wr + 64, AF1);
        stB(cur ^ 1, 0, t1);
        SBAR();
        mm(AF0, BG0, 0, 0);

        // phB: q10 | read bg1 | stage B u1 | BAR
        rdB(pB, wc + 32, BG1);
        stB(cur ^ 1, 1, t1);
        SBAR();
        mm(AF1, BG0, 4, 0);
        BAR();

        // phC: q11 | stage A u0+u1 (t+2 into cur) | vmcnt(4) BAR
        stA(cur, 0, t2);
        stA(cur, 1, t2);
        SBAR();
        mm(AF1, BG1, 4, 2);
        SBAR();
        asm volatile("s_waitcnt vmcnt(4)" ::: "memory");
        BAR();

        // phD: read next tile's af0/bg0 from buf[nxt] | q01 under the drain
        rdA(pAn, wr, AF0n); rdB(pBn, wc, BG0n);
        SBAR();
        mm(AF0, BG1, 0, 2);
    };

    for (int it = 0; it < NT / 2; ++it) {
        ktile(0, it * 2,     af0a, af1a, bg0a, bg1a, af0b, bg0b);
        ktile(1, it * 2 + 1, af0b, af1b, bg0b, bg1b, af0a, bg0a);
    }

    // ---- epilogue: C/D layout col=lane&15, row=(lane>>4)*4+j ----
    const int crow = (lane >> 4) << 2;
    const int ccol = lane & 15;
#pragma unroll
    for (int m = 0; m < 8; ++m) {
#pragma unroll
        for (int n = 0; n < 4; ++n) {
            int col = col0 + wc + n * 16 + ccol;
            float b = bias[col];
#pragma unroll
            for (int j = 0; j < 4; ++j) {
                int row = row0 + wr + m * 16 + crow + j;
                out[(size_t)row * N_DIM + col] = acc[m][n][j] + b;
            }
        }
    }
}

// ---------------- Fallback: fused kernel (if ws too small) ----------------
#define FBM 128
#define FBN 128
#define FTHREADS 256
__global__ __launch_bounds__(FTHREADS) void dq_gemm_fused_kernel(
    const float* __restrict__ x, const int* __restrict__ wq,
    const float* __restrict__ scales, const float* __restrict__ bias,
    float* __restrict__ out)
{
    __shared__ bf16_t fA[FBM * BK];
    __shared__ bf16_t fB[FBN * BK];

    const int tid  = threadIdx.x;
    const int bm   = blockIdx.x / (N_DIM / FBN);
    const int bn   = blockIdx.x % (N_DIM / FBN);
    const int row0 = bm * FBM;
    const int col0 = bn * FBN;
    const int lane = tid & 63;
    const int wid  = tid >> 6;
    const int wr   = (wid >> 1) * 64;
    const int wc   = (wid & 1) * 64;
    const int fr   = lane & 15;
    const int fk   = (lane >> 4) << 3;

    f32x4 acc[4][4];
#pragma unroll
    for (int m = 0; m < 4; ++m)
#pragma unroll
        for (int n = 0; n < 4; ++n) acc[m][n] = (f32x4)0.f;

    for (int kt = 0; kt < K_DIM / BK; ++kt) {
        const int kb = kt * BK;
#pragma unroll
        for (int c = 0; c < 4; ++c) {
            int i  = c * FTHREADS + tid;
            int r  = i >> 3;
            int k0 = (i & 7) << 3;
            const float* gp = x + (size_t)(row0 + r) * K_DIM + kb + k0;
            f32x4 f0 = *(const f32x4*)gp;
            f32x4 f1 = *(const f32x4*)(gp + 4);
            bf16x8 v;
            v[0] = (bf16_t)f0[0]; v[1] = (bf16_t)f0[1];
            v[2] = (bf16_t)f0[2]; v[3] = (bf16_t)f0[3];
            v[4] = (bf16_t)f1[0]; v[5] = (bf16_t)f1[1];
            v[6] = (bf16_t)f1[2]; v[7] = (bf16_t)f1[3];
            *(bf16x8*)&fA[r * BK + (k0 ^ ((r & 7) << 3))] = v;
        }
#pragma unroll
        for (int c = 0; c < 4; ++c) {
            int i  = c * FTHREADS + tid;
            int r  = i >> 3;
            int k0 = (i & 7) << 3;
            int o  = col0 + r;
            const int* gq = wq + (size_t)o * K_DIM + kb + k0;
            i32x4 q0 = *(const i32x4*)gq;
            i32x4 q1 = *(const i32x4*)(gq + 4);
            float s = scales[o * NBLK + ((kb + k0) >> 5)];
            bf16x8 v;
            v[0] = (bf16_t)((float)q0[0] * s); v[1] = (bf16_t)((float)q0[1] * s);
            v[2] = (bf16_t)((float)q0[2] * s); v[3] = (bf16_t)((float)q0[3] * s);
            v[4] = (bf16_t)((float)q1[0] * s); v[5] = (bf16_t)((float)q1[1] * s);
            v[6] = (bf16_t)((float)q1[2] * s); v[7] = (bf16_t)((float)q1[3] * s);
            *(bf16x8*)&fB[r * BK + (k0 ^ ((r & 7) << 3))] = v;
        }
        __syncthreads();
#pragma unroll
        for (int ks = 0; ks < 2; ++ks) {
            bf16x8 af[4], bg[4];
#pragma unroll
            for (int m = 0; m < 4; ++m) {
                int r = wr + m * 16 + fr;
                af[m] = *(const bf16x8*)&fA[r * BK + ((ks * 32 + fk) ^ ((r & 7) << 3))];
            }
#pragma unroll
            for (int n = 0; n < 4; ++n) {
                int r = wc + n * 16 + fr;
                bg[n] = *(const bf16x8*)&fB[r * BK + ((ks * 32 + fk) ^ ((r & 7) << 3))];
            }
#pragma unroll
            for (int m = 0; m < 4; ++m)
#pragma unroll
                for (int n = 0; n < 4; ++n)
                    acc[m][n] = __builtin_amdgcn_mfma_f32_16x16x32_bf16(
                        af[m], bg[n], acc[m][n], 0, 0, 0);
        }
        __syncthreads();
    }

    const int crow = (lane >> 4) << 2;
    const int ccol = lane & 15;
#pragma unroll
    for (int m = 0; m < 4; ++m) {
#pragma unroll
        for (int n = 0; n < 4; ++n) {
            int col = col0 + wc + n * 16 + ccol;
            float b = bias[col];
#pragma unroll
            for (int j = 0; j < 4; ++j) {
                int row = row0 + wr + m * 16 + crow + j;
                out[(size_t)row * N_DIM + col] = acc[m][n][j] + b;
            }
        }
    }
}

extern "C" void kernel_launch(void* const* d_in, const int* in_sizes, int n_in,
                              void* d_out, int out_size, void* d_ws, size_t ws_size,
                              hipStream_t stream) {
    const float* x      = (const float*)d_in[0];
    const int*   wq     = (const int*)d_in[1];
    const float* scales = (const float*)d_in[2];
    const float* bias   = (const float*)d_in[3];
    float*       out    = (float*)d_out;

    if (ws_size >= W_BYTES + X_BYTES) {
        bf16_t* W = (bf16_t*)d_ws;
        bf16_t* X = (bf16_t*)((char*)d_ws + W_BYTES);
        dequant_w_kernel<<<dim3(N_DIM * K_DIM / 8 / 256), dim3(256), 0, stream>>>(wq, scales, W);
        cvt_x_kernel<<<dim3(M_DIM * K_DIM / 8 / 256), dim3(256), 0, stream>>>(x, X);
        gemm256p_kernel<<<dim3((M_DIM / BM) * (N_DIM / BN)), dim3(THREADS), 0, stream>>>(X, W, bias, out);
    } else {
        dq_gemm_fused_kernel<<<dim3((M_DIM / FBM) * (N_DIM / FBN)), dim3(FTHREADS), 0, stream>>>(
            x, wq, scales, bias, out);
    }
}